// Round 5
// baseline (560.071 us; speedup 1.0000x reference)
//
#include <hip/hip_runtime.h>
#include <hip/hip_bf16.h>

#define N_TOK 4096
#define DIM   1024
#define HID   4096
#define NEXP  8
#define NPOS  8192

#define BKS  64                       // K-tile size in shorts
#define MAXT 40                       // max m-tiles at BM=256
#define G1   (MAXT * (HID/128))       // 1280 ffn1 blocks
#define G2   (MAXT * (DIM/128) * 2)   // 640 ffn2 blocks (split-K=2)
#define ABUF (256*64)                 // shorts per A LDS buffer
#define BBUF (128*64)                 // shorts per B LDS buffer

typedef float  f32x4  __attribute__((ext_vector_type(4)));
typedef __bf16 bf16x8 __attribute__((ext_vector_type(8)));
typedef unsigned short us8 __attribute__((ext_vector_type(8)));

__device__ __forceinline__ unsigned short f2bf(float f) {
  __hip_bfloat16 h = __float2bfloat16(f);
  return *reinterpret_cast<unsigned short*>(&h);
}
__device__ __forceinline__ void gload16(const void* g, void* l) {
  __builtin_amdgcn_global_load_lds(
      (const __attribute__((address_space(1))) unsigned int*)g,
      (__attribute__((address_space(3))) unsigned int*)l, 16, 0, 0);
}
#define BAR() __builtin_amdgcn_s_barrier()

// ================= pipelined grouped-GEMM core =================
// BM=256, BN=128, BK=64, 512 threads (8 waves, 4M x 2N).
// 3 LDS buffers; stages run 2 K-tiles ahead; one counted vmcnt(6) per K-tile.
// T2 swizzle: LDS[row][c] holds G[row][c ^ fs(row)], fs(row)=((row>>2)&3)<<4 shorts.
template<int NKT>
__device__ __forceinline__ void gemm_core(
    const unsigned short* a0, const unsigned short* a1,
    const unsigned short* a2, const unsigned short* a3,
    const unsigned short* b0, const unsigned short* b1,
    unsigned short* As, unsigned short* Bs, f32x4 (&acc)[4][4])
{
  const int tid = threadIdx.x;
  const int w = tid >> 6, l = tid & 63;
  const int wm = (w >> 1) * 64, wn = (w & 1) * 64;
  const int ks = (l >> 4) * 8;                    // k-slot within 32
  const int fs = (((l & 15) >> 2) & 3) << 4;      // read-side swizzle
  const int k0 = ks ^ fs;                         // kk=0 col (swizzled)
  const int k1 = (32 | ks) ^ fs;                  // kk=1 col (swizzled)
  int ab[4], bb[4];
#pragma unroll
  for (int m = 0; m < 4; m++) ab[m] = (wm + m*16 + (l & 15)) * 64;
#pragma unroll
  for (int n = 0; n < 4; n++) bb[n] = (wn + n*16 + (l & 15)) * 64;

  auto STG_A = [&](int kt, int sb, int r, const unsigned short* src) {
    gload16(src + kt*BKS, (char*)As + sb*(ABUF*2) + r*8192 + tid*16);
  };
  auto STG_B = [&](int kt, int sb, int r, const unsigned short* src) {
    gload16(src + kt*BKS, (char*)Bs + sb*(BBUF*2) + r*8192 + tid*16);
  };

  // prologue: stage tiles 0 and 1 fully (12 gloads/wave)
  STG_A(0,0,0,a0); STG_A(0,0,1,a1); STG_A(0,0,2,a2);
  STG_A(0,0,3,a3); STG_B(0,0,0,b0); STG_B(0,0,1,b1);
  STG_A(1,1,0,a0); STG_A(1,1,1,a1); STG_A(1,1,2,a2);
  STG_A(1,1,3,a3); STG_B(1,1,0,b0); STG_B(1,1,1,b1);
  asm volatile("s_waitcnt vmcnt(6)" ::: "memory");  // tile 0 landed (all waves: via BAR)
  BAR();

  int cb = 0, sb = 2;
#pragma unroll 1
  for (int t = 0; t < NKT; ++t) {
    const unsigned short* Ac = As + cb * ABUF;
    const unsigned short* Bc = Bs + cb * BBUF;
    const bool st = (t + 2) < NKT;
    bf16x8 af[4], bf[4];
    // ---- phase 0 (kk=0) ----
#pragma unroll
    for (int m = 0; m < 4; m++) af[m] = *reinterpret_cast<const bf16x8*>(Ac + ab[m] + k0);
#pragma unroll
    for (int n = 0; n < 4; n++) bf[n] = *reinterpret_cast<const bf16x8*>(Bc + bb[n] + k0);
    if (st) { STG_A(t+2,sb,0,a0); STG_A(t+2,sb,1,a1); STG_A(t+2,sb,2,a2); }
    BAR();
    __builtin_amdgcn_s_setprio(1);
#pragma unroll
    for (int m = 0; m < 4; m++)
#pragma unroll
      for (int n = 0; n < 4; n++)
        acc[m][n] = __builtin_amdgcn_mfma_f32_16x16x32_bf16(af[m], bf[n], acc[m][n], 0, 0, 0);
    __builtin_amdgcn_s_setprio(0);
    BAR();
    // ---- phase 1 (kk=1) ----
#pragma unroll
    for (int m = 0; m < 4; m++) af[m] = *reinterpret_cast<const bf16x8*>(Ac + ab[m] + k1);
#pragma unroll
    for (int n = 0; n < 4; n++) bf[n] = *reinterpret_cast<const bf16x8*>(Bc + bb[n] + k1);
    if (st) { STG_A(t+2,sb,3,a3); STG_B(t+2,sb,0,b0); STG_B(t+2,sb,1,b1); }
    BAR();
    __builtin_amdgcn_s_setprio(1);
#pragma unroll
    for (int m = 0; m < 4; m++)
#pragma unroll
      for (int n = 0; n < 4; n++)
        acc[m][n] = __builtin_amdgcn_mfma_f32_16x16x32_bf16(af[m], bf[n], acc[m][n], 0, 0, 0);
    __builtin_amdgcn_s_setprio(0);
    if (t < NKT - 2) { asm volatile("s_waitcnt vmcnt(6)" ::: "memory"); }
    else             { asm volatile("s_waitcnt vmcnt(0)" ::: "memory"); }
    BAR();   // after this barrier every wave's loads for tile t+1 have landed
    cb = cb + 1; if (cb == 3) cb = 0;
    sb = sb + 1; if (sb == 3) sb = 0;
  }
}

// ---------------- gating + x->bf16 (fused) ----------------
__global__ __launch_bounds__(256) void gate_kernel(
    const float* __restrict__ x, const float* __restrict__ Wg,
    const float* __restrict__ bg, int* __restrict__ topk_idx,
    float* __restrict__ topk_w, int* __restrict__ expert_count,
    unsigned short* __restrict__ xb)
{
  const int wave = threadIdx.x >> 6, lane = threadIdx.x & 63;
  const int t = blockIdx.x * 4 + wave;
  const float* xr = x + (size_t)t * DIM;
  unsigned short* xbr = xb + (size_t)t * DIM;

  float acc[NEXP];
#pragma unroll
  for (int e = 0; e < NEXP; e++) acc[e] = 0.f;
  for (int d = lane; d < DIM; d += 64) {
    float xv = xr[d];
    xbr[d] = f2bf(xv);
    const f32x4* wr = reinterpret_cast<const f32x4*>(Wg + (size_t)d * NEXP);
    f32x4 w0 = wr[0], w1 = wr[1];
    acc[0] += xv * w0.x; acc[1] += xv * w0.y; acc[2] += xv * w0.z; acc[3] += xv * w0.w;
    acc[4] += xv * w1.x; acc[5] += xv * w1.y; acc[6] += xv * w1.z; acc[7] += xv * w1.w;
  }
#pragma unroll
  for (int e = 0; e < NEXP; e++) {
#pragma unroll
    for (int off = 32; off > 0; off >>= 1)
      acc[e] += __shfl_xor(acc[e], off, 64);
  }
  if (lane == 0) {
    float s[NEXP];
#pragma unroll
    for (int e = 0; e < NEXP; e++) s[e] = acc[e] + bg[e];
    int i0 = 0; float b0 = s[0];
#pragma unroll
    for (int e = 1; e < NEXP; e++) if (s[e] > b0) { b0 = s[e]; i0 = e; }
    int i1 = -1; float b1v = -3.4e38f;
#pragma unroll
    for (int e = 0; e < NEXP; e++) if (e != i0 && s[e] > b1v) { b1v = s[e]; i1 = e; }
    float e1 = __expf(b1v - b0);
    float inv = 1.f / (1.f + e1);
    topk_idx[t*2]   = i0;  topk_idx[t*2+1] = i1;
    topk_w[t*2]     = inv; topk_w[t*2+1]   = e1 * inv;
    atomicAdd(&expert_count[i0], 1);
    atomicAdd(&expert_count[i1], 1);
  }
}

// ---------------- routing: scan + tables + deterministic scatter ----------------
__global__ void route_kernel(const int* __restrict__ expert_count,
                             int* __restrict__ expert_offset,
                             int* __restrict__ table, int* __restrict__ nt,
                             const int* __restrict__ topk_idx,
                             const float* __restrict__ topk_w,
                             int* __restrict__ pair_token, float* __restrict__ pair_w)
{
  __shared__ int soff[NEXP];
  if (threadIdx.x == 0) {
    int off = 0, a = 0;
    for (int e = 0; e < NEXP; e++) {
      expert_offset[e] = off; soff[e] = off;
      int c = expert_count[e];
      for (int r = 0; r < c; r += 256) {
        table[a*4+0] = e; table[a*4+1] = off + r;
        table[a*4+2] = (c - r) < 256 ? (c - r) : 256; a++;
      }
      off += c;
    }
    expert_offset[NEXP] = off;
    *nt = a;
  }
  __syncthreads();
  const int e = threadIdx.x >> 6;
  const int lane = threadIdx.x & 63;
  int base = soff[e];
  for (int a0 = 0; a0 < NPOS; a0 += 64) {
    int a = a0 + lane;
    int idx = topk_idx[a];
    bool f = (idx == e);
    unsigned long long m = __ballot(f);
    if (f) {
      int pos = base + __popcll(m & ((1ull << lane) - 1ull));
      pair_token[pos] = a >> 1;
      pair_w[pos]     = topk_w[a];
    }
    base += __popcll(m);
  }
}

// ---------------- weight transpose+convert [E][R][C] f32 -> [E][C][R] bf16 ------
__global__ __launch_bounds__(256) void transpose_kernel(const float* __restrict__ src,
                                                        unsigned short* __restrict__ dst,
                                                        int R, int C)
{
  __shared__ float S[64][67];
  const int e = blockIdx.z;
  const float* s = src + (size_t)e * R * C;
  unsigned short* d = dst + (size_t)e * R * C;
  const int r0 = blockIdx.y * 64, c0 = blockIdx.x * 64;
  const int tid = threadIdx.x;
  {
    const int rr = tid >> 2, cc = (tid & 3) * 16;
    const float* sp = s + (size_t)(r0 + rr) * C + c0 + cc;
#pragma unroll
    for (int j = 0; j < 4; j++) {
      f32x4 v = *reinterpret_cast<const f32x4*>(sp + j * 4);
      S[rr][cc + j*4 + 0] = v.x;
      S[rr][cc + j*4 + 1] = v.y;
      S[rr][cc + j*4 + 2] = v.z;
      S[rr][cc + j*4 + 3] = v.w;
    }
  }
  __syncthreads();
  {
    const int hh = tid >> 2, dbase = (tid & 3) * 16;
    us8 o0, o1;
#pragma unroll
    for (int i = 0; i < 8; i++) o0[i] = f2bf(S[dbase + i][hh]);
#pragma unroll
    for (int i = 0; i < 8; i++) o1[i] = f2bf(S[dbase + 8 + i][hh]);
    unsigned short* dp = d + (size_t)(c0 + hh) * R + r0 + dbase;
    *reinterpret_cast<us8*>(dp)     = o0;
    *reinterpret_cast<us8*>(dp + 8) = o1;
  }
}

// ---------------- FFN1: h = relu(xb[tok] @ Wt1^T + b1) -> bf16 ----------------
__global__ __launch_bounds__(512, 1) void ffn1_kernel(
    const unsigned short* __restrict__ xb, const unsigned short* __restrict__ Wt1,
    const float* __restrict__ b1, const int* __restrict__ pair_token,
    const int* __restrict__ table, const int* __restrict__ nt,
    unsigned short* __restrict__ h_buf)
{
  __shared__ __align__(16) unsigned short As[3*ABUF];   // 96 KiB
  __shared__ __align__(16) unsigned short Bs[3*BBUF];   // 48 KiB
  __shared__ int tok[256];

  int wg = blockIdx.x;                         // G1 = 1280, 1280%8==0
  wg = (wg & 7) * (G1/8) + (wg >> 3);
  const int mt = wg % MAXT;
  const int n0 = (wg / MAXT) * 128;
  if (mt >= *nt) return;
  const int e = table[mt*4+0], row_start = table[mt*4+1], rows_valid = table[mt*4+2];

  const int tid = threadIdx.x;
  if (tid < 256) tok[tid] = pair_token[row_start + (tid < rows_valid ? tid : 0)];
  __syncthreads();

  const int srcoff = ((tid & 7) * 8) ^ (((tid >> 5) & 3) << 4);  // inverse swizzle on source
  const int srw = tid >> 3;
  const unsigned short* a0 = xb + (size_t)tok[srw      ] * DIM + srcoff;
  const unsigned short* a1 = xb + (size_t)tok[ 64 + srw] * DIM + srcoff;
  const unsigned short* a2 = xb + (size_t)tok[128 + srw] * DIM + srcoff;
  const unsigned short* a3 = xb + (size_t)tok[192 + srw] * DIM + srcoff;
  const unsigned short* We = Wt1 + (size_t)e * HID * DIM;
  const unsigned short* b0p = We + (size_t)(n0 +      srw) * DIM + srcoff;
  const unsigned short* b1p = We + (size_t)(n0 + 64 + srw) * DIM + srcoff;

  f32x4 acc[4][4];
#pragma unroll
  for (int m = 0; m < 4; m++)
#pragma unroll
    for (int n = 0; n < 4; n++) acc[m][n] = (f32x4){0.f, 0.f, 0.f, 0.f};

  gemm_core<DIM/BKS>(a0, a1, a2, a3, b0p, b1p, As, Bs, acc);

  const int w = tid >> 6, l = tid & 63;
  const int wm = (w >> 1) * 64, wn = (w & 1) * 64;
  const int crow = (l >> 4) * 4, ccol = l & 15;
#pragma unroll
  for (int n = 0; n < 4; n++) {
    const int cg = n0 + wn + n*16 + ccol;
    const float bias = b1[(size_t)e * HID + cg];
#pragma unroll
    for (int m = 0; m < 4; m++) {
#pragma unroll
      for (int j = 0; j < 4; j++) {
        int r = wm + m*16 + crow + j;
        if (r < rows_valid)
          h_buf[(size_t)(row_start + r) * HID + cg] = f2bf(fmaxf(acc[m][n][j] + bias, 0.f));
      }
    }
  }
}

// ---------------- FFN2 (split-K=2): out[t] += w * (h @ Wt2^T + b2) ----------------
__global__ __launch_bounds__(512, 1) void ffn2_kernel(
    const unsigned short* __restrict__ h_buf, const unsigned short* __restrict__ Wt2,
    const float* __restrict__ b2, const int* __restrict__ pair_token,
    const float* __restrict__ pair_w, const int* __restrict__ table,
    const int* __restrict__ nt, float* __restrict__ out)
{
  __shared__ __align__(16) unsigned short As[3*ABUF];
  __shared__ __align__(16) unsigned short Bs[3*BBUF];

  int wg = blockIdx.x;                         // G2 = 640, 640%8==0
  wg = (wg & 7) * (G2/8) + (wg >> 3);
  const int kh  = wg / (MAXT * 8);
  const int rem = wg % (MAXT * 8);
  const int mt  = rem % MAXT;
  const int n0  = (rem / MAXT) * 128;
  if (mt >= *nt) return;
  const int e = table[mt*4+0], row_start = table[mt*4+1], rows_valid = table[mt*4+2];

  const int tid = threadIdx.x;
  const int srcoff = ((tid & 7) * 8) ^ (((tid >> 5) & 3) << 4);
  const int srw = tid >> 3;
  const int kofs = kh * (HID / 2);             // split-K offset in shorts

  int r0 = row_start +       srw; if (r0 > NPOS-1) r0 = NPOS-1;
  int r1 = row_start +  64 + srw; if (r1 > NPOS-1) r1 = NPOS-1;
  int r2 = row_start + 128 + srw; if (r2 > NPOS-1) r2 = NPOS-1;
  int r3 = row_start + 192 + srw; if (r3 > NPOS-1) r3 = NPOS-1;

  const unsigned short* a0 = h_buf + (size_t)r0 * HID + kofs + srcoff;
  const unsigned short* a1 = h_buf + (size_t)r1 * HID + kofs + srcoff;
  const unsigned short* a2 = h_buf + (size_t)r2 * HID + kofs + srcoff;
  const unsigned short* a3 = h_buf + (size_t)r3 * HID + kofs + srcoff;
  const unsigned short* We = Wt2 + (size_t)e * DIM * HID;
  const unsigned short* b0p = We + (size_t)(n0 +      srw) * HID + kofs + srcoff;
  const unsigned short* b1p = We + (size_t)(n0 + 64 + srw) * HID + kofs + srcoff;

  f32x4 acc[4][4];
#pragma unroll
  for (int m = 0; m < 4; m++)
#pragma unroll
    for (int n = 0; n < 4; n++) acc[m][n] = (f32x4){0.f, 0.f, 0.f, 0.f};

  gemm_core<(HID/2)/BKS>(a0, a1, a2, a3, b0p, b1p, As, Bs, acc);

  const int w = tid >> 6, l = tid & 63;
  const int wm = (w >> 1) * 64, wn = (w & 1) * 64;
  const int crow = (l >> 4) * 4, ccol = l & 15;
  float bias[4];
#pragma unroll
  for (int n = 0; n < 4; n++)
    bias[n] = (kh == 0) ? b2[(size_t)e * DIM + n0 + wn + n*16 + ccol] : 0.f;

#pragma unroll
  for (int m = 0; m < 4; m++) {
#pragma unroll
    for (int j = 0; j < 4; j++) {
      int r = wm + m*16 + crow + j;
      if (r < rows_valid) {
        int pos = row_start + r;
        int t   = pair_token[pos];
        float wv = pair_w[pos];
        float* orow = out + (size_t)t * DIM;
#pragma unroll
        for (int n = 0; n < 4; n++)
          atomicAdd(&orow[n0 + wn + n*16 + ccol], (acc[m][n][j] + bias[n]) * wv);
      }
    }
  }
}

extern "C" void kernel_launch(void* const* d_in, const int* in_sizes, int n_in,
                              void* d_out, int out_size, void* d_ws, size_t ws_size,
                              hipStream_t stream) {
  const float* x  = (const float*)d_in[0];
  const float* Wg = (const float*)d_in[1];
  const float* bg = (const float*)d_in[2];
  const float* W1 = (const float*)d_in[3];
  const float* b1 = (const float*)d_in[4];
  const float* W2 = (const float*)d_in[5];
  const float* b2 = (const float*)d_in[6];
  float* out = (float*)d_out;

  char* ws = (char*)d_ws;
  const size_t MB = 1024 * 1024;
  int*   expert_count  = (int*)(ws + 0);
  int*   nt            = (int*)(ws + 64);
  int*   expert_offset = (int*)(ws + 128);
  int*   table         = (int*)(ws + 256);
  int*   topk_idx      = (int*)(ws + 4096);
  float* topk_w        = (float*)(ws + 4096 + 32768);
  int*   pair_token    = (int*)(ws + 4096 + 65536);
  float* pair_w        = (float*)(ws + 4096 + 98304);
  unsigned short* xb   = (unsigned short*)(ws + 1*MB);    //  8 MiB
  unsigned short* Wt1  = (unsigned short*)(ws + 9*MB);    // 64 MiB

  const bool roomy = ws_size >= 201ull * MB;
  unsigned short* Wt2 = roomy ? (unsigned short*)(ws + 73*MB) : Wt1;
  unsigned short* h   = roomy ? (unsigned short*)(ws + 137*MB)
                              : (unsigned short*)(ws + 73*MB);

  hipMemsetAsync(ws, 0, 256, stream);
  hipMemsetAsync(d_out, 0, (size_t)N_TOK * DIM * sizeof(float), stream);

  gate_kernel<<<N_TOK / 4, 256, 0, stream>>>(x, Wg, bg, topk_idx, topk_w,
                                             expert_count, xb);
  route_kernel<<<1, 512, 0, stream>>>(expert_count, expert_offset, table, nt,
                                      topk_idx, topk_w, pair_token, pair_w);
  // Wt1 = W1^T per expert: [D][H] -> [H][D]
  transpose_kernel<<<dim3(HID/64, DIM/64, NEXP), 256, 0, stream>>>(W1, Wt1, DIM, HID);
  ffn1_kernel<<<G1, 512, 0, stream>>>(xb, Wt1, b1, pair_token, table, nt, h);
  // Wt2 = W2^T per expert: [H][D] -> [D][H]
  transpose_kernel<<<dim3(DIM/64, HID/64, NEXP), 256, 0, stream>>>(W2, Wt2, HID, DIM);
  ffn2_kernel<<<G2, 512, 0, stream>>>(h, Wt2, b2, pair_token, pair_w, table, nt, out);
}